// Round 13
// baseline (584.885 us; speedup 1.0000x reference)
//
#include <hip/hip_runtime.h>
#include <hip/hip_bf16.h>

#define IN_DIM  512
#define HID     1024
#define OUT_DIM 512
#define BATCH   4096
#define T_STEPS 32

typedef __attribute__((ext_vector_type(8))) short bf16x8;
typedef __attribute__((ext_vector_type(4))) float f32x4;

// 16B fragment load straight to VGPRs. asm so OUR counted vmcnt governs it
// (compiler treats the def as synchronous; the explicit vmcnt ledger is the
// only guard — R8/R12-validated semantics). "memory" pins issue order.
__device__ inline void fload(bf16x8 &d, const __hip_bfloat16* p) {
  asm volatile("global_load_dwordx4 %0, %1, off"
               : "=&v"(d) : "v"(p) : "memory");
}

// D[b][i] = sum_k A[b][k] * W[i][k], then relu(D + bias[i]).
// R13: ZERO LDS, ZERO barriers. BOTH operands fragment-tiled in global
// (layout validated R12): elem (r,k) of a [R][K] matrix lives at
//   ((r>>4)*(K>>5) + (k>>5))*512 + ((k>>3)&3)*128 + (r&15)*8 + (k&7)
// so a wave's MFMA fragment = one contiguous 1KB global_load_dwordx4 at
// base + lane*16 (L2/L1-served; W panel + h panel are XCD-L2-resident via
// the stable batch-panel swizzle).
// Tile 128(b) x 64(i), 4 waves M-stacked (wave 32b x 64i, acc[2][4]),
// 2 blocks/CU. Per-wave depth-2 counted-vmcnt pipeline: 12 loads/tile
// (8 B-frags + 4 A-frags), vmcnt(12) steady, 0 only at tail. T5 setprio.
// Waves never synchronize; latency hidden by 2 waves/SIMD + prefetch.
// Cf: f32 transposed Cf[i*BATCH+b] (nt-store); Cb: h fragment-tiled for the
// next step's A (K_next = HID, Ks = 32), may be null.
__global__ __launch_bounds__(256, 2) void gemm_ft(
    const __hip_bfloat16* __restrict__ At,
    const __hip_bfloat16* __restrict__ Wt,
    const float* __restrict__ bias,
    float* __restrict__ Cf,
    __hip_bfloat16* __restrict__ Cb,
    int K, int nx)
{
  // bijective XCD swizzle (nwg % 8 == 0: 512 or 256)
  const int nwg = gridDim.x;
  const int q   = nwg >> 3;
  const int bid = blockIdx.x;
  const int swz = (bid & 7) * q + (bid >> 3);
  const int bxi = swz % nx;          // neuron-tile index
  const int byi = swz / nx;          // batch-panel index (stable per XCD)
  const int brow = byi * 128;
  const int bcol = bxi * 64;

  const int tid  = threadIdx.x;
  const int lane = tid & 63;
  const int wid  = tid >> 6;          // 0..3, M-stacked
  const int l15  = lane & 15, l4 = lane >> 4;

  const int Ks = K >> 5;              // 32-k slices
  const int nt = K >> 6;              // 8 or 16 (even)

  // fragment base pointers (frag(s) = base + s*512)
  const __hip_bfloat16* wa0 = At + (size_t)((brow >> 4) + wid * 2 + 0) * Ks * 512 + lane * 8;
  const __hip_bfloat16* wa1 = At + (size_t)((brow >> 4) + wid * 2 + 1) * Ks * 512 + lane * 8;
  const __hip_bfloat16* wb0 = Wt + (size_t)((bcol >> 4) + 0) * Ks * 512 + lane * 8;
  const __hip_bfloat16* wb1 = Wt + (size_t)((bcol >> 4) + 1) * Ks * 512 + lane * 8;
  const __hip_bfloat16* wb2 = Wt + (size_t)((bcol >> 4) + 2) * Ks * 512 + lane * 8;
  const __hip_bfloat16* wb3 = Wt + (size_t)((bcol >> 4) + 3) * Ks * 512 + lane * 8;

  f32x4 acc[2][4] = {};

  // two named register banks (rule 20: all indices compile-time)
  bf16x8 bX[4][2], aX[2][2];
  bf16x8 bY[4][2], aY[2][2];

  // 12 loads per tile, fixed issue order (the vmcnt ledger)
  auto loadTile = [&](int ti, bf16x8 (&cb)[4][2], bf16x8 (&ca)[2][2]) {
    const int s0 = ti * 2;
    fload(cb[0][0], wb0 + (s0 + 0) * 512); fload(cb[0][1], wb0 + (s0 + 1) * 512);
    fload(cb[1][0], wb1 + (s0 + 0) * 512); fload(cb[1][1], wb1 + (s0 + 1) * 512);
    fload(cb[2][0], wb2 + (s0 + 0) * 512); fload(cb[2][1], wb2 + (s0 + 1) * 512);
    fload(cb[3][0], wb3 + (s0 + 0) * 512); fload(cb[3][1], wb3 + (s0 + 1) * 512);
    fload(ca[0][0], wa0 + (s0 + 0) * 512); fload(ca[0][1], wa0 + (s0 + 1) * 512);
    fload(ca[1][0], wa1 + (s0 + 0) * 512); fload(ca[1][1], wa1 + (s0 + 1) * 512);
  };

  // ---- prologue: tiles 0,1 in flight (24 outstanding) ----
  loadTile(0, bX, aX);
  loadTile(1, bY, aY);

  auto iterf = [&](int ti, bf16x8 (&cb)[4][2], bf16x8 (&ca)[2][2]) {
    // wait this tile's 12 loads; keep next tile's 12 in flight
    if (ti < nt - 1) {
      asm volatile("s_waitcnt vmcnt(12)" ::: "memory");
    } else {
      asm volatile("s_waitcnt vmcnt(0)" ::: "memory");
    }
    __builtin_amdgcn_sched_barrier(0);   // rule 18: pin MFMAs below the wait

    __builtin_amdgcn_s_setprio(1);
#pragma unroll
    for (int ks = 0; ks < 2; ++ks)
#pragma unroll
      for (int m = 0; m < 2; ++m)
#pragma unroll
        for (int n = 0; n < 4; ++n)
          acc[m][n] = __builtin_amdgcn_mfma_f32_16x16x32_bf16(
              ca[m][ks], cb[n][ks], acc[m][n], 0, 0, 0);
    __builtin_amdgcn_s_setprio(0);
    __builtin_amdgcn_sched_barrier(0);   // pin refill below the MFMAs

    if (ti + 2 < nt) loadTile(ti + 2, cb, ca);   // refill consumed bank
  };

  for (int ti = 0; ti < nt; ti += 2) {
    iterf(ti,     bX, aX);
    iterf(ti + 1, bY, aY);
  }

  // ---- epilogue: bias + relu; Cf nt-store; Cb fragment-tiled (Ks=32) ----
#pragma unroll
  for (int n = 0; n < 4; ++n) {
    const int i = bcol + n * 16 + l15;
    const float bv = bias[i];
    const int ioff = (i >> 5) * 512 + ((i >> 3) & 3) * 128 + (i & 7);
#pragma unroll
    for (int m = 0; m < 2; ++m) {
      const int b0 = brow + wid * 32 + m * 16 + l4 * 4;
      f32x4 v = acc[m][n];
      f32x4 o;
      o[0] = fmaxf(v[0] + bv, 0.0f);
      o[1] = fmaxf(v[1] + bv, 0.0f);
      o[2] = fmaxf(v[2] + bv, 0.0f);
      o[3] = fmaxf(v[3] + bv, 0.0f);
      __builtin_nontemporal_store(o, (f32x4*)(Cf + (size_t)i * BATCH + b0));
      if (Cb) {
        // off(b,i) = ((b>>4)*32 + (i>>5))*512 + ((i>>3)&3)*128 + (b&15)*8 + (i&7)
        // b = b0 + j, (b&15) = l4*4 + j
        const size_t cbase = (size_t)(b0 >> 4) * 16384 + ioff + l4 * 32;
        Cb[cbase +  0] = __float2bfloat16(o[0]);
        Cb[cbase +  8] = __float2bfloat16(o[1]);
        Cb[cbase + 16] = __float2bfloat16(o[2]);
        Cb[cbase + 24] = __float2bfloat16(o[3]);
      }
    }
  }
}

// f32 -> bf16 convert of the 3 weight matrices into FRAGMENT-TILED layout
// (R12-validated). One thread per 8-elem k-chunk.
__global__ __launch_bounds__(256) void convert_weights_tiled(
    const float* __restrict__ w_in, const float* __restrict__ w_rec,
    const float* __restrict__ w_out,
    __hip_bfloat16* __restrict__ wi, __hip_bfloat16* __restrict__ wr,
    __hip_bfloat16* __restrict__ wo)
{
  const int c  = blockIdx.x * blockDim.x + threadIdx.x;
  const int c1 = HID * IN_DIM / 8;
  const int c2 = c1 + HID * HID / 8;
  const int c3 = c2 + OUT_DIM * HID / 8;
  const float* src; __hip_bfloat16* dst; int K, local;
  if (c < c1)      { src = w_in;  dst = wi; K = IN_DIM; local = c; }
  else if (c < c2) { src = w_rec; dst = wr; K = HID;    local = c - c1; }
  else if (c < c3) { src = w_out; dst = wo; K = HID;    local = c - c2; }
  else return;
  const int kc8 = K >> 3;
  const int i  = local / kc8;
  const int k0 = (local - i * kc8) << 3;
  const float4 a = *(const float4*)(src + (size_t)i * K + k0);
  const float4 b = *(const float4*)(src + (size_t)i * K + k0 + 4);
  union { __hip_bfloat16 h[8]; bf16x8 v; } p;
  p.h[0] = __float2bfloat16(a.x); p.h[1] = __float2bfloat16(a.y);
  p.h[2] = __float2bfloat16(a.z); p.h[3] = __float2bfloat16(a.w);
  p.h[4] = __float2bfloat16(b.x); p.h[5] = __float2bfloat16(b.y);
  p.h[6] = __float2bfloat16(b.z); p.h[7] = __float2bfloat16(b.w);
  const size_t off = ((size_t)(i >> 4) * (K >> 5) + (k0 >> 5)) * 512
                   + ((k0 >> 3) & 3) * 128 + (i & 15) * 8;
  *(bf16x8*)(dst + off) = p.v;
}

// x [IN_DIM][BATCH] f32 -> xT fragment-tiled bf16 (A-operand layout, Ks=16):
// elem (b,k) at ((b>>4)*16 + (k>>5))*512 + ((k>>3)&3)*128 + (b&15)*8 + (k&7)
__global__ __launch_bounds__(256) void transpose_x_tiled(
    const float* __restrict__ in, __hip_bfloat16* __restrict__ out)
{
  __shared__ float tile[32][33];
  const int c0 = blockIdx.x * 32;   // batch base
  const int r0 = blockIdx.y * 32;   // k base (one 32-k slice)
  const int tx = threadIdx.x & 31, ty = threadIdx.x >> 5;
#pragma unroll
  for (int dy = 0; dy < 32; dy += 8)
    tile[ty + dy][tx] = in[(size_t)(r0 + ty + dy) * BATCH + c0 + tx];  // [k][b]
  __syncthreads();
  // the 32x32 block = two 512-elem fragment tiles (b-subtiles f=0,1),
  // each stored contiguously; consecutive tid -> consecutive bf16 (coalesced)
#pragma unroll
  for (int r = 0; r < 4; ++r) {
    const int g   = r * 256 + threadIdx.x;    // 0..1023
    const int f   = g >> 9;
    const int idx = g & 511;                  // ((k>>3)&3)*128 + (b&15)*8 + (k&7)
    const int klocal = (idx >> 7) * 8 + (idx & 7);
    const int blocal = f * 16 + ((idx >> 3) & 15);
    const size_t off = ((size_t)((c0 >> 4) + f) * (IN_DIM >> 5) + (r0 >> 5)) * 512 + idx;
    out[off] = __float2bfloat16(tile[klocal][blocal]);
  }
}

extern "C" void kernel_launch(void* const* d_in, const int* in_sizes, int n_in,
                              void* d_out, int out_size, void* d_ws, size_t ws_size,
                              hipStream_t stream)
{
  const float* x     = (const float*)d_in[0];   // [512][4096]
  const float* W_in  = (const float*)d_in[1];   // [1024][512]
  const float* b_in  = (const float*)d_in[2];   // [1024]
  const float* W_rec = (const float*)d_in[3];   // [1024][1024]
  const float* b_rec = (const float*)d_in[4];   // [1024]
  const float* W_out = (const float*)d_in[5];   // [512][1024]
  const float* b_out = (const float*)d_in[6];   // [512]

  float* out0 = (float*)d_out;                        // [512][4096]
  float* itm  = out0 + (size_t)OUT_DIM * BATCH;       // [33][1024][4096]

  __hip_bfloat16* xT = (__hip_bfloat16*)d_ws;         // [4096][512] tiled
  __hip_bfloat16* Wi = xT + (size_t)BATCH * IN_DIM;   // [1024][512] tiled
  __hip_bfloat16* Wr = Wi + (size_t)HID * IN_DIM;     // [1024][1024] tiled
  __hip_bfloat16* Wo = Wr + (size_t)HID * HID;        // [512][1024] tiled
  __hip_bfloat16* h0 = Wo + (size_t)OUT_DIM * HID;    // [4096][1024] tiled
  __hip_bfloat16* h1 = h0 + (size_t)BATCH * HID;      // [4096][1024] tiled

  // input conversions: tile x; convert+tile all 3 weights in one launch
  transpose_x_tiled<<<dim3(BATCH / 32, IN_DIM / 32), 256, 0, stream>>>(x, xT);
  {
    const int nC = (HID * IN_DIM + HID * HID + OUT_DIM * HID) / 8;
    convert_weights_tiled<<<(nC + 255) / 256, 256, 0, stream>>>(
        W_in, W_rec, W_out, Wi, Wr, Wo);
  }

  // y0 = relu(W_in @ x + b_in): grid 512, nx = 16, K = 512
  gemm_ft<<<(HID / 64) * (BATCH / 128), 256, 0, stream>>>(
      xT, Wi, b_in, itm, h0, IN_DIM, HID / 64);

  // 32 recurrent steps: grid 512, nx = 16, K = 1024
  __hip_bfloat16* cur = h0;
  __hip_bfloat16* nxt = h1;
  for (int t = 0; t < T_STEPS; ++t) {
    float* dst = itm + (size_t)(t + 1) * HID * BATCH;
    gemm_ft<<<(HID / 64) * (BATCH / 128), 256, 0, stream>>>(
        cur, Wr, b_rec, dst, nxt, HID, HID / 64);
    __hip_bfloat16* tmp = cur; cur = nxt; nxt = tmp;
  }

  // out = relu(W_out @ h_last + b_out): grid 256, nx = 8, K = 1024
  gemm_ft<<<(OUT_DIM / 64) * (BATCH / 128), 256, 0, stream>>>(
      cur, Wo, b_out, out0, (__hip_bfloat16*)nullptr, HID, OUT_DIM / 64);
}

// Round 15
// 560.766 us; speedup vs baseline: 1.0430x; 1.0430x over previous
//
#include <hip/hip_runtime.h>
#include <hip/hip_bf16.h>

#define IN_DIM  512
#define HID     1024
#define OUT_DIM 512
#define BATCH   4096
#define T_STEPS 32

typedef __attribute__((ext_vector_type(8))) short bf16x8;
typedef __attribute__((ext_vector_type(4))) float f32x4;

__device__ inline void gload16(const void* g, void* l) {
  __builtin_amdgcn_global_load_lds(
      (const __attribute__((address_space(1))) void*)g,
      (__attribute__((address_space(3))) void*)l, 16, 0, 0);
}

// 16B B-fragment load straight to VGPRs (R12-validated vmcnt-ledger semantics).
__device__ inline void bload(bf16x8 &d, const __hip_bfloat16* p) {
  asm volatile("global_load_dwordx4 %0, %1, off"
               : "=&v"(d) : "v"(p) : "memory");
}

// D[b][i] = sum_k A[b][k] * Wt[i][k], then relu(D + bias[i]).
// R15: WAVE-AUTONOMOUS pipelines — zero barriers.
// Block 128(b) x 64(i), BK=64, TWO waves, each owning a 64x64 wave-tile
// (acc[4][4]) and staging ITS OWN 64 A-rows into a wave-private LDS region
// (no cross-wave dependency -> no s_barrier anywhere). B fragment-tiled
// direct-from-L2 (R12), 2x dup across the block's waves, L1-served.
// 128-thr blocks, __launch_bounds__(128,2) -> 4 blocks/CU = 8 independent
// wave pipelines per CU. Counted vmcnt: 16 loads/tile (8 B + 8 A-gloads),
// vmcnt(16) steady, 0 only at tail; wave-local lgkmcnt(0) before re-stage.
// T2 both-sides XOR swizzle on A; T5 setprio; XCD-stable batch panels;
// nt-store Cf; scatter Cb (L2-absorbed, R10).
// Per block-iter: LDS write 16 + read 16 = 32KB (R12: 48); vmem 32KB (=R12).
// A:  [4096][K] bf16 row-major
// Wt: fragment-tiled (R12 layout): elem (i,k) at
//     ((i>>4)*(K>>5) + (k>>5))*512 + ((k>>3)&3)*128 + (i&15)*8 + (k&7)
// Cf: f32 transposed Cf[i*BATCH+b]; Cb: bf16 Cb[b*Nld+i] (may be null)
__global__ __launch_bounds__(128, 2) void gemm_wa(
    const __hip_bfloat16* __restrict__ A,
    const __hip_bfloat16* __restrict__ Wt,
    const float* __restrict__ bias,
    float* __restrict__ Cf,
    __hip_bfloat16* __restrict__ Cb,
    int K, int Nld, int nx)
{
  // bijective XCD swizzle (nwg % 8 == 0: 512 or 256)
  const int nwg = gridDim.x;
  const int q   = nwg >> 3;
  const int bid = blockIdx.x;
  const int swz = (bid & 7) * q + (bid >> 3);
  const int bxi = swz % nx;          // neuron-tile index
  const int byi = swz / nx;          // batch-panel index (stable per XCD)
  const int brow = byi * 128;
  const int bcol = bxi * 64;

  const int tid  = threadIdx.x;
  const int lane = tid & 63;
  const int wid  = tid >> 6;          // 0 or 1: wave owns rows wid*64..+63
  const int l15  = lane & 15, l4 = lane >> 4;
  const int srow = lane >> 3;                   // 8 rows per gload16
  const int schunk = (lane & 7) ^ (srow & 7);   // T2 stage-side pre-swizzle

  // wave-private A staging: [wave][dbuf][64 rows][64 k]
  __shared__ __hip_bfloat16 Alds[2][2][64 * 64];   // 32 KB/block

  f32x4 acc[4][4] = {};
  const int nt = K >> 6;   // 8 or 16 (even)

  // stage THIS wave's 64 rows of K-tile ti: 8 gload16 (8 rows x 64k each)
  const __hip_bfloat16* arow = A + (size_t)(brow + wid * 64 + srow) * K + schunk * 8;
  auto stageA = [&](int ti, int buf) {
    const int kt = ti << 6;
#pragma unroll
    for (int it = 0; it < 8; ++it)
      gload16(arow + (size_t)(it * 8) * K + kt, &Alds[wid][buf][it * 8 * 64]);
  };

  // fragment-tiled W pointers: 4 i-tiles, frag(s) = base + s*512
  const int Ks = K >> 5;
  const __hip_bfloat16* wb0 = Wt + (size_t)((bcol >> 4) + 0) * Ks * 512 + lane * 8;
  const __hip_bfloat16* wb1 = Wt + (size_t)((bcol >> 4) + 1) * Ks * 512 + lane * 8;
  const __hip_bfloat16* wb2 = Wt + (size_t)((bcol >> 4) + 2) * Ks * 512 + lane * 8;
  const __hip_bfloat16* wb3 = Wt + (size_t)((bcol >> 4) + 3) * Ks * 512 + lane * 8;

  // two named register banks for B (rule 20)
  bf16x8 bx[4][2], by[4][2];   // [n][ks]

  auto loadB = [&](int ti, bf16x8 (&cb)[4][2]) {
    const int s0 = ti * 2;
    bload(cb[0][0], wb0 + (s0 + 0) * 512); bload(cb[0][1], wb0 + (s0 + 1) * 512);
    bload(cb[1][0], wb1 + (s0 + 0) * 512); bload(cb[1][1], wb1 + (s0 + 1) * 512);
    bload(cb[2][0], wb2 + (s0 + 0) * 512); bload(cb[2][1], wb2 + (s0 + 1) * 512);
    bload(cb[3][0], wb3 + (s0 + 0) * 512); bload(cb[3][1], wb3 + (s0 + 1) * 512);
  };

  // ---- prologue: tiles 0,1 in flight (32 outstanding), ledger order ----
  loadB(0, bx);
  __builtin_amdgcn_sched_barrier(0);
  stageA(0, 0);
  __builtin_amdgcn_sched_barrier(0);
  loadB(1, by);
  __builtin_amdgcn_sched_barrier(0);
  stageA(1, 1);

  const int rxor = l15 & 7;

  auto iterf = [&](int ti, bf16x8 (&cb)[4][2]) {
    const int buf = ti & 1;
    // wave-local wait: tile ti's 16 loads done; tile ti+1's 16 in flight
    if (ti < nt - 1) {
      asm volatile("s_waitcnt vmcnt(16)" ::: "memory");
    } else {
      asm volatile("s_waitcnt vmcnt(0)" ::: "memory");
    }
    __builtin_amdgcn_sched_barrier(0);   // rule 18: pin ds_reads below wait

    __builtin_amdgcn_s_setprio(1);
#pragma unroll
    for (int ks = 0; ks < 2; ++ks) {
      bf16x8 af[4];
      const int cp = ((ks * 4 + l4) ^ rxor) * 8;   // T2 read-side XOR
#pragma unroll
      for (int m = 0; m < 4; ++m)
        af[m] = *(const bf16x8*)&Alds[wid][buf][(m * 16 + l15) * 64 + cp];
#pragma unroll
      for (int m = 0; m < 4; ++m)
#pragma unroll
        for (int n = 0; n < 4; ++n)
          acc[m][n] = __builtin_amdgcn_mfma_f32_16x16x32_bf16(
              af[m], cb[n][ks], acc[m][n], 0, 0, 0);
    }
    __builtin_amdgcn_s_setprio(0);
    __builtin_amdgcn_sched_barrier(0);   // pin refills below the MFMAs

    if (ti + 2 < nt) {
      loadB(ti + 2, cb);                             // refill B bank
      asm volatile("s_waitcnt lgkmcnt(0)" ::: "memory");  // own ds_reads done
      __builtin_amdgcn_sched_barrier(0);
      stageA(ti + 2, buf);                           // refill own A buf (WAR safe)
    }
  };

  for (int ti = 0; ti < nt; ti += 2) {
    iterf(ti,     bx);
    iterf(ti + 1, by);
  }

  // ---- epilogue: bias + relu, dual store ----
#pragma unroll
  for (int n = 0; n < 4; ++n) {
    const int i = bcol + n * 16 + l15;
    const float bv = bias[i];
#pragma unroll
    for (int m = 0; m < 4; ++m) {
      const int b0 = brow + wid * 64 + m * 16 + l4 * 4;
      f32x4 v = acc[m][n];
      f32x4 o;
      o[0] = fmaxf(v[0] + bv, 0.0f);
      o[1] = fmaxf(v[1] + bv, 0.0f);
      o[2] = fmaxf(v[2] + bv, 0.0f);
      o[3] = fmaxf(v[3] + bv, 0.0f);
      __builtin_nontemporal_store(o, (f32x4*)(Cf + (size_t)i * BATCH + b0));
      if (Cb) {
        Cb[(size_t)(b0 + 0) * Nld + i] = __float2bfloat16(o[0]);
        Cb[(size_t)(b0 + 1) * Nld + i] = __float2bfloat16(o[1]);
        Cb[(size_t)(b0 + 2) * Nld + i] = __float2bfloat16(o[2]);
        Cb[(size_t)(b0 + 3) * Nld + i] = __float2bfloat16(o[3]);
      }
    }
  }
}

// f32 -> bf16 convert of the 3 weight matrices into FRAGMENT-TILED layout
// (R12-validated). One thread per 8-elem k-chunk.
__global__ __launch_bounds__(256) void convert_weights_tiled(
    const float* __restrict__ w_in, const float* __restrict__ w_rec,
    const float* __restrict__ w_out,
    __hip_bfloat16* __restrict__ wi, __hip_bfloat16* __restrict__ wr,
    __hip_bfloat16* __restrict__ wo)
{
  const int c  = blockIdx.x * blockDim.x + threadIdx.x;
  const int c1 = HID * IN_DIM / 8;
  const int c2 = c1 + HID * HID / 8;
  const int c3 = c2 + OUT_DIM * HID / 8;
  const float* src; __hip_bfloat16* dst; int K, local;
  if (c < c1)      { src = w_in;  dst = wi; K = IN_DIM; local = c; }
  else if (c < c2) { src = w_rec; dst = wr; K = HID;    local = c - c1; }
  else if (c < c3) { src = w_out; dst = wo; K = HID;    local = c - c2; }
  else return;
  const int kc8 = K >> 3;
  const int i  = local / kc8;
  const int k0 = (local - i * kc8) << 3;
  const float4 a = *(const float4*)(src + (size_t)i * K + k0);
  const float4 b = *(const float4*)(src + (size_t)i * K + k0 + 4);
  union { __hip_bfloat16 h[8]; bf16x8 v; } p;
  p.h[0] = __float2bfloat16(a.x); p.h[1] = __float2bfloat16(a.y);
  p.h[2] = __float2bfloat16(a.z); p.h[3] = __float2bfloat16(a.w);
  p.h[4] = __float2bfloat16(b.x); p.h[5] = __float2bfloat16(b.y);
  p.h[6] = __float2bfloat16(b.z); p.h[7] = __float2bfloat16(b.w);
  const size_t off = ((size_t)(i >> 4) * (K >> 5) + (k0 >> 5)) * 512
                   + ((k0 >> 3) & 3) * 128 + (i & 15) * 8;
  *(bf16x8*)(dst + off) = p.v;
}

// in[R][C] f32 -> out[C][R] bf16 (LDS 32x32 tile transpose)
__global__ __launch_bounds__(256) void transpose_f32_bf16(
    const float* __restrict__ in, __hip_bfloat16* __restrict__ out, int R, int C)
{
  __shared__ float tile[32][33];
  const int c0 = blockIdx.x * 32, r0 = blockIdx.y * 32;
  const int tx = threadIdx.x & 31, ty = threadIdx.x >> 5;
#pragma unroll
  for (int dy = 0; dy < 32; dy += 8)
    tile[ty + dy][tx] = in[(size_t)(r0 + ty + dy) * C + c0 + tx];
  __syncthreads();
#pragma unroll
  for (int dy = 0; dy < 32; dy += 8)
    out[(size_t)(c0 + ty + dy) * R + r0 + tx] = __float2bfloat16(tile[tx][ty + dy]);
}

extern "C" void kernel_launch(void* const* d_in, const int* in_sizes, int n_in,
                              void* d_out, int out_size, void* d_ws, size_t ws_size,
                              hipStream_t stream)
{
  const float* x     = (const float*)d_in[0];   // [512][4096]
  const float* W_in  = (const float*)d_in[1];   // [1024][512]
  const float* b_in  = (const float*)d_in[2];   // [1024]
  const float* W_rec = (const float*)d_in[3];   // [1024][1024]
  const float* b_rec = (const float*)d_in[4];   // [1024]
  const float* W_out = (const float*)d_in[5];   // [512][1024]
  const float* b_out = (const float*)d_in[6];   // [512]

  float* out0 = (float*)d_out;                        // [512][4096]
  float* itm  = out0 + (size_t)OUT_DIM * BATCH;       // [33][1024][4096]

  __hip_bfloat16* xT = (__hip_bfloat16*)d_ws;         // [4096][512]
  __hip_bfloat16* Wi = xT + (size_t)BATCH * IN_DIM;   // [1024][512] tiled
  __hip_bfloat16* Wr = Wi + (size_t)HID * IN_DIM;     // [1024][1024] tiled
  __hip_bfloat16* Wo = Wr + (size_t)HID * HID;        // [512][1024] tiled
  __hip_bfloat16* h0 = Wo + (size_t)OUT_DIM * HID;    // [4096][1024]
  __hip_bfloat16* h1 = h0 + (size_t)BATCH * HID;      // [4096][1024]

  // input conversions: transpose x; convert+tile all 3 weights in one launch
  transpose_f32_bf16<<<dim3(BATCH / 32, IN_DIM / 32), 256, 0, stream>>>(x, xT, IN_DIM, BATCH);
  {
    const int nC = (HID * IN_DIM + HID * HID + OUT_DIM * HID) / 8;
    convert_weights_tiled<<<(nC + 255) / 256, 256, 0, stream>>>(
        W_in, W_rec, W_out, Wi, Wr, Wo);
  }

  // y0 = relu(W_in @ x + b_in): grid 512, nx = 16, K = 512
  gemm_wa<<<(HID / 64) * (BATCH / 128), 128, 0, stream>>>(
      xT, Wi, b_in, itm, h0, IN_DIM, HID, HID / 64);

  // 32 recurrent steps: grid 512, nx = 16, K = 1024
  __hip_bfloat16* cur = h0;
  __hip_bfloat16* nxt = h1;
  for (int t = 0; t < T_STEPS; ++t) {
    float* dst = itm + (size_t)(t + 1) * HID * BATCH;
    gemm_wa<<<(HID / 64) * (BATCH / 128), 128, 0, stream>>>(
        cur, Wr, b_rec, dst, nxt, HID, HID, HID / 64);
    __hip_bfloat16* tmp = cur; cur = nxt; nxt = tmp;
  }

  // out = relu(W_out @ h_last + b_out): grid 256, nx = 8, K = 1024
  gemm_wa<<<(OUT_DIM / 64) * (BATCH / 128), 128, 0, stream>>>(
      cur, Wo, b_out, out0, (__hip_bfloat16*)nullptr, HID, 0, OUT_DIM / 64);
}

// Round 16
// 527.350 us; speedup vs baseline: 1.1091x; 1.0634x over previous
//
#include <hip/hip_runtime.h>
#include <hip/hip_bf16.h>

#define IN_DIM  512
#define HID     1024
#define OUT_DIM 512
#define BATCH   4096
#define T_STEPS 32

typedef __attribute__((ext_vector_type(8))) short bf16x8;
typedef __attribute__((ext_vector_type(4))) float f32x4;

__device__ inline void gload16(const void* g, void* l) {
  __builtin_amdgcn_global_load_lds(
      (const __attribute__((address_space(1))) void*)g,
      (__attribute__((address_space(3))) void*)l, 16, 0, 0);
}

// 16B B-fragment load straight to VGPRs (R12-validated vmcnt-ledger semantics).
__device__ inline void bload(bf16x8 &d, const __hip_bfloat16* p) {
  asm volatile("global_load_dwordx4 %0, %1, off"
               : "=&v"(d) : "v"(p) : "memory");
}

// D[b][i] = sum_k A[b][k] * Wt[i][k], then relu(D + bias[i]).
// R16 = R12 with BK=128: same bytes, HALF the K-iterations -> half the
// barrier/wait convoy events per step (32 -> 16), 32-MFMA runs per iter.
// Tile 128(b) x 64(i), 4 waves (2x2), 2 blocks/CU (LDS 2x64KB=128<=160).
// B fragment-tiled direct-from-L2 (8 floads/tile); A LDS-staged dbuf
// (8 gload16/tile/wave, 4 rows each); counted vmcnt: 16 ops/tile,
// vmcnt(16) steady, 0 only at tail. T2 both-sides XOR swizzle (4-bit chunk,
// XOR low 3 bits — each ds_read_b128 stays at its 8-dword/bank floor).
// T5 setprio; XCD-stable batch panels; nt-store Cf; scatter Cb.
// A:  [4096][K] bf16 row-major
// Wt: fragment-tiled (R12 layout): elem (i,k) at
//     ((i>>4)*(K>>5) + (k>>5))*512 + ((k>>3)&3)*128 + (i&15)*8 + (k&7)
// Cf: f32 transposed Cf[i*BATCH+b]; Cb: bf16 Cb[b*Nld+i] (may be null)
__global__ __launch_bounds__(256, 2) void gemm_bt_bias_relu(
    const __hip_bfloat16* __restrict__ A,
    const __hip_bfloat16* __restrict__ Wt,
    const float* __restrict__ bias,
    float* __restrict__ Cf,
    __hip_bfloat16* __restrict__ Cb,
    int K, int Nld, int nx)
{
  // bijective XCD swizzle (nwg % 8 == 0: 512 or 256)
  const int nwg = gridDim.x;
  const int q   = nwg >> 3;
  const int bid = blockIdx.x;
  const int swz = (bid & 7) * q + (bid >> 3);
  const int bxi = swz % nx;          // neuron-tile index
  const int byi = swz / nx;          // batch-panel index (stable per XCD)
  const int brow = byi * 128;
  const int bcol = bxi * 64;

  const int tid  = threadIdx.x;
  const int lane = tid & 63;
  const int wid  = tid >> 6;
  const int wr   = wid >> 1, wc = wid & 1;   // 2x2 waves: wave tile 64(b) x 32(i)
  const int l15  = lane & 15, l4 = lane >> 4;

  __shared__ __hip_bfloat16 Alds[2][128 * 128];  // 2 x 32 KB

  f32x4 acc[4][2] = {};
  const int nt = K >> 7;   // K/128: 4 or 8 (even)

  // stage one 128x128 A-tile: 8 gload16/wave; each covers 4 rows x 16 chunks.
  // T2 stage-side: physical chunk (lane&15) holds logical (lane&15)^(row&7).
  auto stageA = [&](int ti, int buf) {
    const int kt = ti << 7;
#pragma unroll
    for (int it = 0; it < 8; ++it) {
      const int rowbase = it * 16 + wid * 4;           // wave-uniform
      const int row = rowbase + (lane >> 4);
      const int sc  = (lane & 15) ^ (row & 7);
      gload16(A + (size_t)(brow + row) * K + kt + sc * 8,
              &Alds[buf][rowbase * 128]);
    }
  };

  // fragment-tiled W pointers: frag(slice s) = wt[n] + s*512
  const int Ks = K >> 5;
  const __hip_bfloat16* wt[2];
  wt[0] = Wt + (size_t)((bcol >> 4) + wc * 2 + 0) * Ks * 512 + lane * 8;
  wt[1] = Wt + (size_t)((bcol >> 4) + wc * 2 + 1) * Ks * 512 + lane * 8;

  // two named register banks for B (rule 20): [n][slice 0..3]
  bf16x8 bx[2][4], by[2][4];

  auto loadB = [&](int ti, bf16x8 (&cb)[2][4]) {
    const int s0 = ti * 4;
#pragma unroll
    for (int n = 0; n < 2; ++n)
#pragma unroll
      for (int s = 0; s < 4; ++s)
        bload(cb[n][s], wt[n] + (s0 + s) * 512);
  };

  // ---- prologue: tiles 0,1 in flight (32 outstanding), ledger order ----
  loadB(0, bx);
  __builtin_amdgcn_sched_barrier(0);
  stageA(0, 0);
  __builtin_amdgcn_sched_barrier(0);
  loadB(1, by);
  __builtin_amdgcn_sched_barrier(0);
  stageA(1, 1);

  const int rxor = l15 & 7;

  auto iterf = [&](int ti, bf16x8 (&cb)[2][4]) {
    const int buf = ti & 1;
    // T4: tile ti's 16 loads done; tile ti+1's 16 stay in flight
    if (ti < nt - 1) {
      asm volatile("s_waitcnt vmcnt(16)" ::: "memory");
    } else {
      asm volatile("s_waitcnt vmcnt(0)" ::: "memory");
    }
    __builtin_amdgcn_s_barrier();
    __builtin_amdgcn_sched_barrier(0);   // rule 18: pin ds_reads below the wait

    __builtin_amdgcn_s_setprio(1);
#pragma unroll
    for (int ks = 0; ks < 4; ++ks) {
      bf16x8 af[4];
      const int cp = ((ks * 4 + l4) ^ rxor) * 8;   // T2 read-side XOR (16 chunks)
#pragma unroll
      for (int m = 0; m < 4; ++m)
        af[m] = *(const bf16x8*)&Alds[buf][(wr * 64 + m * 16 + l15) * 128 + cp];
#pragma unroll
      for (int m = 0; m < 4; ++m)
#pragma unroll
        for (int n = 0; n < 2; ++n)
          acc[m][n] = __builtin_amdgcn_mfma_f32_16x16x32_bf16(
              af[m], cb[n][ks], acc[m][n], 0, 0, 0);
    }
    __builtin_amdgcn_s_setprio(0);
    __builtin_amdgcn_sched_barrier(0);   // keep refills below the MFMAs (WAR)

    if (ti + 2 < nt) loadB(ti + 2, cb);  // refill B bank for tile ti+2

    asm volatile("s_waitcnt lgkmcnt(0)" ::: "memory");  // all reads of buf done
    __builtin_amdgcn_sched_barrier(0);
    __builtin_amdgcn_s_barrier();
    __builtin_amdgcn_sched_barrier(0);
    if (ti + 2 < nt) stageA(ti + 2, buf);               // refill consumed A buf
  };

  for (int ti = 0; ti < nt; ti += 2) {
    iterf(ti,     bx);
    iterf(ti + 1, by);
  }

  // ---- epilogue: bias + relu, dual store (R12 form) ----
#pragma unroll
  for (int n = 0; n < 2; ++n) {
    const int i = bcol + wc * 32 + n * 16 + l15;
    const float bv = bias[i];
#pragma unroll
    for (int m = 0; m < 4; ++m) {
      const int b0 = brow + wr * 64 + m * 16 + l4 * 4;
      f32x4 v = acc[m][n];
      f32x4 o;
      o[0] = fmaxf(v[0] + bv, 0.0f);
      o[1] = fmaxf(v[1] + bv, 0.0f);
      o[2] = fmaxf(v[2] + bv, 0.0f);
      o[3] = fmaxf(v[3] + bv, 0.0f);
      __builtin_nontemporal_store(o, (f32x4*)(Cf + (size_t)i * BATCH + b0));
      if (Cb) {
        Cb[(size_t)(b0 + 0) * Nld + i] = __float2bfloat16(o[0]);
        Cb[(size_t)(b0 + 1) * Nld + i] = __float2bfloat16(o[1]);
        Cb[(size_t)(b0 + 2) * Nld + i] = __float2bfloat16(o[2]);
        Cb[(size_t)(b0 + 3) * Nld + i] = __float2bfloat16(o[3]);
      }
    }
  }
}

// f32 -> bf16 convert of the 3 weight matrices into FRAGMENT-TILED layout
// (R12-validated). One thread per 8-elem k-chunk.
__global__ __launch_bounds__(256) void convert_weights_tiled(
    const float* __restrict__ w_in, const float* __restrict__ w_rec,
    const float* __restrict__ w_out,
    __hip_bfloat16* __restrict__ wi, __hip_bfloat16* __restrict__ wr,
    __hip_bfloat16* __restrict__ wo)
{
  const int c  = blockIdx.x * blockDim.x + threadIdx.x;
  const int c1 = HID * IN_DIM / 8;
  const int c2 = c1 + HID * HID / 8;
  const int c3 = c2 + OUT_DIM * HID / 8;
  const float* src; __hip_bfloat16* dst; int K, local;
  if (c < c1)      { src = w_in;  dst = wi; K = IN_DIM; local = c; }
  else if (c < c2) { src = w_rec; dst = wr; K = HID;    local = c - c1; }
  else if (c < c3) { src = w_out; dst = wo; K = HID;    local = c - c2; }
  else return;
  const int kc8 = K >> 3;
  const int i  = local / kc8;
  const int k0 = (local - i * kc8) << 3;
  const float4 a = *(const float4*)(src + (size_t)i * K + k0);
  const float4 b = *(const float4*)(src + (size_t)i * K + k0 + 4);
  union { __hip_bfloat16 h[8]; bf16x8 v; } p;
  p.h[0] = __float2bfloat16(a.x); p.h[1] = __float2bfloat16(a.y);
  p.h[2] = __float2bfloat16(a.z); p.h[3] = __float2bfloat16(a.w);
  p.h[4] = __float2bfloat16(b.x); p.h[5] = __float2bfloat16(b.y);
  p.h[6] = __float2bfloat16(b.z); p.h[7] = __float2bfloat16(b.w);
  const size_t off = ((size_t)(i >> 4) * (K >> 5) + (k0 >> 5)) * 512
                   + ((k0 >> 3) & 3) * 128 + (i & 15) * 8;
  *(bf16x8*)(dst + off) = p.v;
}

// in[R][C] f32 -> out[C][R] bf16 (LDS 32x32 tile transpose)
__global__ __launch_bounds__(256) void transpose_f32_bf16(
    const float* __restrict__ in, __hip_bfloat16* __restrict__ out, int R, int C)
{
  __shared__ float tile[32][33];
  const int c0 = blockIdx.x * 32, r0 = blockIdx.y * 32;
  const int tx = threadIdx.x & 31, ty = threadIdx.x >> 5;
#pragma unroll
  for (int dy = 0; dy < 32; dy += 8)
    tile[ty + dy][tx] = in[(size_t)(r0 + ty + dy) * C + c0 + tx];
  __syncthreads();
#pragma unroll
  for (int dy = 0; dy < 32; dy += 8)
    out[(size_t)(c0 + ty + dy) * R + r0 + tx] = __float2bfloat16(tile[tx][ty + dy]);
}

extern "C" void kernel_launch(void* const* d_in, const int* in_sizes, int n_in,
                              void* d_out, int out_size, void* d_ws, size_t ws_size,
                              hipStream_t stream)
{
  const float* x     = (const float*)d_in[0];   // [512][4096]
  const float* W_in  = (const float*)d_in[1];   // [1024][512]
  const float* b_in  = (const float*)d_in[2];   // [1024]
  const float* W_rec = (const float*)d_in[3];   // [1024][1024]
  const float* b_rec = (const float*)d_in[4];   // [1024]
  const float* W_out = (const float*)d_in[5];   // [512][1024]
  const float* b_out = (const float*)d_in[6];   // [512]

  float* out0 = (float*)d_out;                        // [512][4096]
  float* itm  = out0 + (size_t)OUT_DIM * BATCH;       // [33][1024][4096]

  __hip_bfloat16* xT = (__hip_bfloat16*)d_ws;         // [4096][512]
  __hip_bfloat16* Wi = xT + (size_t)BATCH * IN_DIM;   // [1024][512] tiled
  __hip_bfloat16* Wr = Wi + (size_t)HID * IN_DIM;     // [1024][1024] tiled
  __hip_bfloat16* Wo = Wr + (size_t)HID * HID;        // [512][1024] tiled
  __hip_bfloat16* h0 = Wo + (size_t)OUT_DIM * HID;    // [4096][1024]
  __hip_bfloat16* h1 = h0 + (size_t)BATCH * HID;      // [4096][1024]

  // input conversions: transpose x; convert+tile all 3 weights in one launch
  transpose_f32_bf16<<<dim3(BATCH / 32, IN_DIM / 32), 256, 0, stream>>>(x, xT, IN_DIM, BATCH);
  {
    const int nC = (HID * IN_DIM + HID * HID + OUT_DIM * HID) / 8;
    convert_weights_tiled<<<(nC + 255) / 256, 256, 0, stream>>>(
        W_in, W_rec, W_out, Wi, Wr, Wo);
  }

  // y0 = relu(W_in @ x + b_in): grid 512, nx = 16, K = 512 (nt = 4)
  gemm_bt_bias_relu<<<(HID / 64) * (BATCH / 128), 256, 0, stream>>>(
      xT, Wi, b_in, itm, h0, IN_DIM, HID, HID / 64);

  // 32 recurrent steps: grid 512, nx = 16, K = 1024 (nt = 8)
  __hip_bfloat16* cur = h0;
  __hip_bfloat16* nxt = h1;
  for (int t = 0; t < T_STEPS; ++t) {
    float* dst = itm + (size_t)(t + 1) * HID * BATCH;
    gemm_bt_bias_relu<<<(HID / 64) * (BATCH / 128), 256, 0, stream>>>(
        cur, Wr, b_rec, dst, nxt, HID, HID, HID / 64);
    __hip_bfloat16* tmp = cur; cur = nxt; nxt = tmp;
  }

  // out = relu(W_out @ h_last + b_out): grid 256, nx = 8
  gemm_bt_bias_relu<<<(OUT_DIM / 64) * (BATCH / 128), 256, 0, stream>>>(
      cur, Wo, b_out, out0, (__hip_bfloat16*)nullptr, HID, 0, OUT_DIM / 64);
}

// Round 17
// 494.794 us; speedup vs baseline: 1.1821x; 1.0658x over previous
//
#include <hip/hip_runtime.h>
#include <hip/hip_bf16.h>

#define IN_DIM  512
#define HID     1024
#define OUT_DIM 512
#define BATCH   4096
#define T_STEPS 32

typedef __attribute__((ext_vector_type(8))) short bf16x8;
typedef __attribute__((ext_vector_type(4))) float f32x4;

__device__ inline void gload16(const void* g, void* l) {
  __builtin_amdgcn_global_load_lds(
      (const __attribute__((address_space(1))) void*)g,
      (__attribute__((address_space(3))) void*)l, 16, 0, 0);
}

// 16B B-fragment load straight to VGPRs (R12-validated vmcnt-ledger semantics).
__device__ inline void bload(bf16x8 &d, const __hip_bfloat16* p) {
  asm volatile("global_load_dwordx4 %0, %1, off"
               : "=&v"(d) : "v"(p) : "memory");
}

// D[b][i] = sum_k A[b][k] * Wt[i][k], then relu(D + bias[i]).
// R17 = R12 geometry exactly (tile 128x64, BK=64, 4 waves 2x2, 2 blocks/CU,
// 2 barriers/iter — the barrier lockstep is load-locality glue, proven by
// R6/R15/R16 regressions) with ISSUE-LEVEL interleave inside the skeleton:
//  - B refills split per-slice, each placed right after the MFMA group that
//    last consumes that slice (register WAR keeps order; cb[*][0] dead after
//    ks=0 group) -> refill issue overlaps MFMA execution.
//  - over-pinning sched_barriers inside the compute region removed so the
//    compiler can weave ks=1 ds_reads under ks=0 MFMAs.
// vmcnt ledger UNCHANGED: per tile issue order [B0 x2, B1 x2, A x4] = 8 ops;
// vmcnt(8) at top of iter == tile ti fully landed, ti+1 in flight.
// B fragment-tiled direct-from-L2 (R12 layout); A LDS-staged dbuf with T2
// both-sides XOR swizzle; T5 setprio; XCD-stable batch panels; nt-store Cf;
// scatter Cb (L2-absorbed).
// A:  [4096][K] bf16 row-major
// Wt: fragment-tiled: elem (i,k) at
//     ((i>>4)*(K>>5) + (k>>5))*512 + ((k>>3)&3)*128 + (i&15)*8 + (k&7)
// Cf: f32 transposed Cf[i*BATCH+b]; Cb: bf16 Cb[b*Nld+i] (may be null)
__global__ __launch_bounds__(256, 2) void gemm_bt_bias_relu(
    const __hip_bfloat16* __restrict__ A,
    const __hip_bfloat16* __restrict__ Wt,
    const float* __restrict__ bias,
    float* __restrict__ Cf,
    __hip_bfloat16* __restrict__ Cb,
    int K, int Nld, int nx)
{
  // bijective XCD swizzle (nwg % 8 == 0: 512 or 256)
  const int nwg = gridDim.x;
  const int q   = nwg >> 3;
  const int bid = blockIdx.x;
  const int swz = (bid & 7) * q + (bid >> 3);
  const int bxi = swz % nx;          // neuron-tile index
  const int byi = swz / nx;          // batch-panel index (stable per XCD)
  const int brow = byi * 128;
  const int bcol = bxi * 64;

  const int tid  = threadIdx.x;
  const int lane = tid & 63;
  const int wid  = tid >> 6;
  const int wr   = wid >> 1, wc = wid & 1;   // 2x2 waves: wave tile 64(b) x 32(i)
  const int l15  = lane & 15, l4 = lane >> 4;
  const int srow = lane >> 3;
  const int schunk = (lane & 7) ^ (srow & 7);   // T2 stage-side pre-swizzle

  __shared__ __hip_bfloat16 Alds[2][128 * 64];  // 2 x 16 KB

  f32x4 acc[4][2] = {};
  const int nt = K >> 6;   // 8 or 16 (even)

  // A staging: 4 gload16 per wave per tile
  auto stageA = [&](int ti, int buf) {
    const int kt = ti << 6;
#pragma unroll
    for (int it = 0; it < 4; ++it) {
      const int rowbase = it * 32 + wid * 8;           // wave-uniform LDS base
      gload16(A + (size_t)(brow + rowbase + srow) * K + kt + schunk * 8,
              &Alds[buf][rowbase * 64]);
    }
  };

  // fragment-tiled W pointers: frag(slice s) = wt[n] + s*512
  const int Ks = K >> 5;
  const __hip_bfloat16* wt0 = Wt + (size_t)((bcol >> 4) + wc * 2 + 0) * Ks * 512 + lane * 8;
  const __hip_bfloat16* wt1 = Wt + (size_t)((bcol >> 4) + wc * 2 + 1) * Ks * 512 + lane * 8;

  // two named register banks for B (rule 20): [n][ks]
  bf16x8 bx00, bx01, bx10, bx11;
  bf16x8 by00, by01, by10, by11;

  // ---- prologue: ledger order B(0) | A(0) | B(1) | A(1) ----
  bload(bx00, wt0 + 0 * 512); bload(bx10, wt1 + 0 * 512);
  bload(bx01, wt0 + 1 * 512); bload(bx11, wt1 + 1 * 512);
  __builtin_amdgcn_sched_barrier(0);
  stageA(0, 0);
  __builtin_amdgcn_sched_barrier(0);
  bload(by00, wt0 + 2 * 512); bload(by10, wt1 + 2 * 512);
  bload(by01, wt0 + 3 * 512); bload(by11, wt1 + 3 * 512);
  __builtin_amdgcn_sched_barrier(0);
  stageA(1, 1);

  const int rxor = l15 & 7;

  // one pipeline iteration; c* = B regs for tile ti (refilled for ti+2)
  auto iterf = [&](int ti,
                   bf16x8 &c00, bf16x8 &c01, bf16x8 &c10, bf16x8 &c11) {
    const int buf = ti & 1;
    // T4: tile ti's 8 loads done; tile ti+1's 8 stay in flight
    if (ti < nt - 1) {
      asm volatile("s_waitcnt vmcnt(8)" ::: "memory");
    } else {
      asm volatile("s_waitcnt vmcnt(0)" ::: "memory");
    }
    __builtin_amdgcn_s_barrier();
    __builtin_amdgcn_sched_barrier(0);   // rule 18: nothing hoists above the wait

    const int s0 = (ti + 2) * 2;
    const bool refill = (ti + 2 < nt);

    __builtin_amdgcn_s_setprio(1);
    // ---- ks = 0 group (consumes c00, c10) ----
    {
      bf16x8 af[4];
      const int cp = ((0 * 4 + l4) ^ rxor) * 8;
#pragma unroll
      for (int m = 0; m < 4; ++m)
        af[m] = *(const bf16x8*)&Alds[buf][(wr * 64 + m * 16 + l15) * 64 + cp];
#pragma unroll
      for (int m = 0; m < 4; ++m) {
        acc[m][0] = __builtin_amdgcn_mfma_f32_16x16x32_bf16(af[m], c00, acc[m][0], 0, 0, 0);
        acc[m][1] = __builtin_amdgcn_mfma_f32_16x16x32_bf16(af[m], c10, acc[m][1], 0, 0, 0);
      }
    }
    // refill slice 0 of this bank (c00/c10 now dead; reg WAR keeps order)
    if (refill) {
      bload(c00, wt0 + (size_t)(s0 + 0) * 512);
      bload(c10, wt1 + (size_t)(s0 + 0) * 512);
    }
    // ---- ks = 1 group (consumes c01, c11) ----
    {
      bf16x8 af[4];
      const int cp = ((1 * 4 + l4) ^ rxor) * 8;
#pragma unroll
      for (int m = 0; m < 4; ++m)
        af[m] = *(const bf16x8*)&Alds[buf][(wr * 64 + m * 16 + l15) * 64 + cp];
#pragma unroll
      for (int m = 0; m < 4; ++m) {
        acc[m][0] = __builtin_amdgcn_mfma_f32_16x16x32_bf16(af[m], c01, acc[m][0], 0, 0, 0);
        acc[m][1] = __builtin_amdgcn_mfma_f32_16x16x32_bf16(af[m], c11, acc[m][1], 0, 0, 0);
      }
    }
    __builtin_amdgcn_s_setprio(0);
    // refill slice 1
    if (refill) {
      bload(c01, wt0 + (size_t)(s0 + 1) * 512);
      bload(c11, wt1 + (size_t)(s0 + 1) * 512);
    }

    asm volatile("s_waitcnt lgkmcnt(0)" ::: "memory");  // all ds_reads of buf done
    __builtin_amdgcn_sched_barrier(0);
    __builtin_amdgcn_s_barrier();                       // all waves done with buf
    __builtin_amdgcn_sched_barrier(0);                  // pin stage below barrier
    if (refill) stageA(ti + 2, buf);                    // refill consumed A buf
  };

  for (int ti = 0; ti < nt; ti += 2) {
    iterf(ti,     bx00, bx01, bx10, bx11);
    iterf(ti + 1, by00, by01, by10, by11);
  }

  // ---- epilogue: bias + relu, dual store (R12 form) ----
#pragma unroll
  for (int n = 0; n < 2; ++n) {
    const int i = bcol + wc * 32 + n * 16 + l15;
    const float bv = bias[i];
#pragma unroll
    for (int m = 0; m < 4; ++m) {
      const int b0 = brow + wr * 64 + m * 16 + l4 * 4;
      f32x4 v = acc[m][n];
      f32x4 o;
      o[0] = fmaxf(v[0] + bv, 0.0f);
      o[1] = fmaxf(v[1] + bv, 0.0f);
      o[2] = fmaxf(v[2] + bv, 0.0f);
      o[3] = fmaxf(v[3] + bv, 0.0f);
      __builtin_nontemporal_store(o, (f32x4*)(Cf + (size_t)i * BATCH + b0));
      if (Cb) {
        Cb[(size_t)(b0 + 0) * Nld + i] = __float2bfloat16(o[0]);
        Cb[(size_t)(b0 + 1) * Nld + i] = __float2bfloat16(o[1]);
        Cb[(size_t)(b0 + 2) * Nld + i] = __float2bfloat16(o[2]);
        Cb[(size_t)(b0 + 3) * Nld + i] = __float2bfloat16(o[3]);
      }
    }
  }
}

// f32 -> bf16 convert of the 3 weight matrices into FRAGMENT-TILED layout
// (R12-validated). One thread per 8-elem k-chunk.
__global__ __launch_bounds__(256) void convert_weights_tiled(
    const float* __restrict__ w_in, const float* __restrict__ w_rec,
    const float* __restrict__ w_out,
    __hip_bfloat16* __restrict__ wi, __hip_bfloat16* __restrict__ wr,
    __hip_bfloat16* __restrict__ wo)
{
  const int c  = blockIdx.x * blockDim.x + threadIdx.x;
  const int c1 = HID * IN_DIM / 8;
  const int c2 = c1 + HID * HID / 8;
  const int c3 = c2 + OUT_DIM * HID / 8;
  const float* src; __hip_bfloat16* dst; int K, local;
  if (c < c1)      { src = w_in;  dst = wi; K = IN_DIM; local = c; }
  else if (c < c2) { src = w_rec; dst = wr; K = HID;    local = c - c1; }
  else if (c < c3) { src = w_out; dst = wo; K = HID;    local = c - c2; }
  else return;
  const int kc8 = K >> 3;
  const int i  = local / kc8;
  const int k0 = (local - i * kc8) << 3;
  const float4 a = *(const float4*)(src + (size_t)i * K + k0);
  const float4 b = *(const float4*)(src + (size_t)i * K + k0 + 4);
  union { __hip_bfloat16 h[8]; bf16x8 v; } p;
  p.h[0] = __float2bfloat16(a.x); p.h[1] = __float2bfloat16(a.y);
  p.h[2] = __float2bfloat16(a.z); p.h[3] = __float2bfloat16(a.w);
  p.h[4] = __float2bfloat16(b.x); p.h[5] = __float2bfloat16(b.y);
  p.h[6] = __float2bfloat16(b.z); p.h[7] = __float2bfloat16(b.w);
  const size_t off = ((size_t)(i >> 4) * (K >> 5) + (k0 >> 5)) * 512
                   + ((k0 >> 3) & 3) * 128 + (i & 15) * 8;
  *(bf16x8*)(dst + off) = p.v;
}

// in[R][C] f32 -> out[C][R] bf16 (LDS 32x32 tile transpose)
__global__ __launch_bounds__(256) void transpose_f32_bf16(
    const float* __restrict__ in, __hip_bfloat16* __restrict__ out, int R, int C)
{
  __shared__ float tile[32][33];
  const int c0 = blockIdx.x * 32, r0 = blockIdx.y * 32;
  const int tx = threadIdx.x & 31, ty = threadIdx.x >> 5;
#pragma unroll
  for (int dy = 0; dy < 32; dy += 8)
    tile[ty + dy][tx] = in[(size_t)(r0 + ty + dy) * C + c0 + tx];
  __syncthreads();
#pragma unroll
  for (int dy = 0; dy < 32; dy += 8)
    out[(size_t)(c0 + ty + dy) * R + r0 + tx] = __float2bfloat16(tile[tx][ty + dy]);
}

extern "C" void kernel_launch(void* const* d_in, const int* in_sizes, int n_in,
                              void* d_out, int out_size, void* d_ws, size_t ws_size,
                              hipStream_t stream)
{
  const float* x     = (const float*)d_in[0];   // [512][4096]
  const float* W_in  = (const float*)d_in[1];   // [1024][512]
  const float* b_in  = (const float*)d_in[2];   // [1024]
  const float* W_rec = (const float*)d_in[3];   // [1024][1024]
  const float* b_rec = (const float*)d_in[4];   // [1024]
  const float* W_out = (const float*)d_in[5];   // [512][1024]
  const float* b_out = (const float*)d_in[6];   // [512]

  float* out0 = (float*)d_out;                        // [512][4096]
  float* itm  = out0 + (size_t)OUT_DIM * BATCH;       // [33][1024][4096]

  __hip_bfloat16* xT = (__hip_bfloat16*)d_ws;         // [4096][512]
  __hip_bfloat16* Wi = xT + (size_t)BATCH * IN_DIM;   // [1024][512] tiled
  __hip_bfloat16* Wr = Wi + (size_t)HID * IN_DIM;     // [1024][1024] tiled
  __hip_bfloat16* Wo = Wr + (size_t)HID * HID;        // [512][1024] tiled
  __hip_bfloat16* h0 = Wo + (size_t)OUT_DIM * HID;    // [4096][1024]
  __hip_bfloat16* h1 = h0 + (size_t)BATCH * HID;      // [4096][1024]

  // input conversions: transpose x; convert+tile all 3 weights in one launch
  transpose_f32_bf16<<<dim3(BATCH / 32, IN_DIM / 32), 256, 0, stream>>>(x, xT, IN_DIM, BATCH);
  {
    const int nC = (HID * IN_DIM + HID * HID + OUT_DIM * HID) / 8;
    convert_weights_tiled<<<(nC + 255) / 256, 256, 0, stream>>>(
        W_in, W_rec, W_out, Wi, Wr, Wo);
  }

  // y0 = relu(W_in @ x + b_in): grid 512, nx = 16, K = 512
  gemm_bt_bias_relu<<<(HID / 64) * (BATCH / 128), 256, 0, stream>>>(
      xT, Wi, b_in, itm, h0, IN_DIM, HID, HID / 64);

  // 32 recurrent steps: grid 512, nx = 16, K = 1024
  __hip_bfloat16* cur = h0;
  __hip_bfloat16* nxt = h1;
  for (int t = 0; t < T_STEPS; ++t) {
    float* dst = itm + (size_t)(t + 1) * HID * BATCH;
    gemm_bt_bias_relu<<<(HID / 64) * (BATCH / 128), 256, 0, stream>>>(
        cur, Wr, b_rec, dst, nxt, HID, HID, HID / 64);
    __hip_bfloat16* tmp = cur; cur = nxt; nxt = tmp;
  }

  // out = relu(W_out @ h_last + b_out): grid 256, nx = 8
  gemm_bt_bias_relu<<<(OUT_DIM / 64) * (BATCH / 128), 256, 0, stream>>>(
      cur, Wo, b_out, out0, (__hip_bfloat16*)nullptr, HID, 0, OUT_DIM / 64);
}